// Round 16
// baseline (535.469 us; speedup 1.0000x reference)
//
#include <hip/hip_runtime.h>
#include <cstdint>

using u64 = unsigned long long;

// ---------------- weight bit-packing ----------------
__global__ void pack_conv_weights(const float* __restrict__ w, u64* __restrict__ wb,
                                  int Cin, int Cout) {
    int cinw = Cin >> 6;
    int total = 9 * cinw * Cout;
    int idx = blockIdx.x * blockDim.x + threadIdx.x;
    if (idx >= total) return;
    int co = idx % Cout;
    int rest = idx / Cout;
    int wd = rest % cinw;
    int t = rest / cinw;
    u64 word = 0ull;
    for (int b = 0; b < 64; ++b) {
        int ci = (wd << 6) + b;
        float v = w[(t * Cin + ci) * Cout + co];
        if (v >= 0.f) word |= (1ull << b);
    }
    wb[idx] = word;
}

__global__ void pack_dense_weights(const float* __restrict__ w, u64* __restrict__ wb) {
    int j = blockIdx.x * blockDim.x + threadIdx.x;
    if (j >= 1000) return;
    for (int wd = 0; wd < 8; ++wd) {
        u64 word = 0ull;
        for (int b = 0; b < 64; ++b) {
            float v = w[((wd << 6) + b) * 1000 + j];
            if (v >= 0.f) word |= (1ull << b);
        }
        wb[j * 8 + wd] = word;
    }
}

// ---------------- per-channel BN sign thresholds (f64, computed once) ----------------
// v >= 0  <=>  (s>=0 ? r >= thr : r <= thr), s = g*rsqrt(var+eps), thr = mu - be/s
__global__ void prep_bnthr(const float* __restrict__ bn, int cout,
                           double* __restrict__ thrd, int* __restrict__ sflag) {
    int i = blockIdx.x * blockDim.x + threadIdx.x;
    if (i >= cout) return;
    double g  = (double)bn[i];
    double be = (double)bn[cout + i];
    double mu = (double)bn[2 * cout + i];
    double va = (double)bn[3 * cout + i];
    double s  = g * (1.0 / sqrt(va + 1e-3));
    thrd[i] = mu - be / s;
    sflag[i] = (s >= 0.0) ? 1 : 0;
}

__global__ void prep_thrf(const double* __restrict__ thrd, float* __restrict__ thrf) {
    int i = threadIdx.x;
    if (i < 64) thrf[i] = (float)thrd[i];
}

// ---------------- stage 1: fp conv 3->64 + bias + relu + BN + maxpool + sign ----------------
// R14-verified (146 us): one wave x 4 pooled pixels; per-pixel 4x4x3 patch in registers;
// f32 main path vs precomputed threshold; f64 fixup only in |rf-thr|<TAU band.
// launch_bounds(256,1): VGPR ~104, no spill. (256,4) would cap VGPR at 64 -> spill (R7).
__global__ __launch_bounds__(256, 1)
void conv1_fused(const float* __restrict__ in, const float* __restrict__ w,
                 const float* __restrict__ bias,
                 const float* __restrict__ thrf, const double* __restrict__ thrd,
                 const int* __restrict__ sflag,
                 u64* __restrict__ outbits) {
    int lane = threadIdx.x & 63;
    int wid = blockIdx.x * (blockDim.x >> 6) + (threadIdx.x >> 6);  // 16*112*28 waves
    int pxq = wid % 28;
    int py  = (wid / 28) % 112;
    int n   = wid / (28 * 112);

    float  thrv = thrf[lane];
    double thrD = thrd[lane];
    bool   spos = (sflag[lane] != 0);
    float  bif  = bias[lane];

    float wreg[27];
#pragma unroll
    for (int t = 0; t < 9; ++t)
#pragma unroll
        for (int c = 0; c < 3; ++c)
            wreg[t * 3 + c] = w[(t * 3 + c) * 64 + lane];

    const float TAU = 2e-4f;
    int iy0 = 2 * py - 1;
    bool rowint = (py >= 1) & (py <= 110);

#pragma unroll 1
    for (int pp = 0; pp < 4; ++pp) {
        int px = 4 * pxq + pp;
        int ix0 = 2 * px - 1;

        float patch[4][12];
        bool interior = rowint & (px >= 1) & (px <= 110);
        if (interior) {
            const float* base = in + ((size_t)(n * 224 + iy0) * 224 + ix0) * 3;
#pragma unroll
            for (int r = 0; r < 4; ++r) {
                const float* rp = base + (size_t)r * (224 * 3);
#pragma unroll
                for (int c = 0; c < 12; ++c) patch[r][c] = rp[c];
            }
        } else {
#pragma unroll
            for (int r = 0; r < 4; ++r) {
                int iy = iy0 + r;
                bool rv = (iy >= 0) & (iy < 224);
#pragma unroll
                for (int cc = 0; cc < 4; ++cc) {
                    int ix = ix0 + cc;
                    bool v = rv & (ix >= 0) & (ix < 224);
                    const float* p = in + ((size_t)(n * 224 + iy) * 224 + ix) * 3;
#pragma unroll
                    for (int c = 0; c < 3; ++c)
                        patch[r][cc * 3 + c] = v ? p[c] : 0.f;
                }
            }
        }

        bool pred = false;
#pragma unroll
        for (int q = 0; q < 4; ++q) {
            int qy = q >> 1, qx = q & 1;
            float accf = bif;
#pragma unroll
            for (int dy = 0; dy < 3; ++dy)
#pragma unroll
                for (int dx = 0; dx < 3; ++dx)
#pragma unroll
                    for (int c = 0; c < 3; ++c)
                        accf = fmaf(patch[qy + dy][(qx + dx) * 3 + c],
                                    wreg[(dy * 3 + dx) * 3 + c], accf);
            float rf = fmaxf(accf, 0.f);
            bool p = spos ? (rf >= thrv) : (rf <= thrv);
            if (fabsf(rf - thrv) < TAU) {
                double acc = (double)bif;
#pragma unroll
                for (int dy = 0; dy < 3; ++dy)
#pragma unroll
                    for (int dx = 0; dx < 3; ++dx)
#pragma unroll
                        for (int c = 0; c < 3; ++c)
                            acc = fma((double)patch[qy + dy][(qx + dx) * 3 + c],
                                      (double)wreg[(dy * 3 + dx) * 3 + c], acc);
                double rd = fmax(acc, 0.0);
                p = spos ? (rd >= thrD) : (rd <= thrD);
            }
            pred |= p;                    // sign(max) = max(sign) -> OR over 2x2 pool
        }
        u64 word = __ballot(pred);
        if (lane == 0) outbits[((size_t)(n * 112 + py)) * 112 + px] = word;
    }
}

// ---------------- generic binary conv + relu + BN + sign ----------------
// R=2 output rows per block: 4 staged input rows serve 2 output rows (1.5x less
// staging), the 9 weight words per column-group serve BOTH rows (2x fewer weight
// loads), and block count halves (less launch/sync overhead). LDS reads are
// thread-uniform broadcasts (R15 lesson: never conflicted). Input-row validity is a
// wave-uniform skip; border taps via closed-form nvp = ndy*(3-eL-eR).
// Live regs per w-iter: wt[9] (18 VGPR) + acc[2][P] (16) + v — under the default cap.
// NO launch_bounds (R7/R10: explicit bounds here backfire).
template<int CINW, int COUT, int P, int R, bool OUTF64>
__global__ void bconv(const u64* __restrict__ xin, const u64* __restrict__ wb,
                      const float* __restrict__ bn,
                      const double* __restrict__ thrd, const int* __restrict__ sflag,
                      u64* __restrict__ obits, double* __restrict__ of64,
                      int H, int W) {
    constexpr int CW = COUT >> 6;
    __shared__ u64 sh[R + 2][P + 2][CINW];

    int tid = threadIdx.x;  // = co
    int XT = W / P;
    int YT = H / R;
    int pos = blockIdx.x;
    int xt = pos % XT;
    int yt = (pos / XT) % YT;
    int n  = pos / (XT * YT);
    int x0 = xt * P;
    int y0 = yt * R;

    for (int i = tid; i < (R + 2) * (P + 2) * CINW; i += COUT) {
        int wd = i % CINW;
        int cc = (i / CINW) % (P + 2);
        int rr = i / (CINW * (P + 2));
        int gy = y0 - 1 + rr, gx = x0 - 1 + cc;
        u64 v = 0ull;
        if (gy >= 0 && gy < H && gx >= 0 && gx < W)
            v = xin[((size_t)(n * H + gy) * W + gx) * CINW + wd];
        sh[rr][cc][wd] = v;
    }
    __syncthreads();

    int acc[R][P];
#pragma unroll
    for (int r = 0; r < R; ++r)
#pragma unroll
        for (int p = 0; p < P; ++p) acc[r][p] = 0;

    int co = tid;
    bool leftv  = (x0 > 0);        // column c=0   (gx = x0-1) valid?
    bool rightv = (x0 + P < W);    // column c=P+1 (gx = x0+P) valid?

#pragma unroll 1
    for (int w = 0; w < CINW; ++w) {
        u64 wt[9];
#pragma unroll
        for (int t = 0; t < 9; ++t)
            wt[t] = wb[(t * CINW + w) * COUT + co];
        // LDS row rr holds input row y0+rr-1; it serves output r (0<=r<R) with
        // tap dy = rr - r (0<=dy<=2).
#pragma unroll
        for (int rr = 0; rr < R + 2; ++rr) {
            int gy = y0 + rr - 1;
            if (gy < 0 || gy >= H) continue;   // uniform across block
#pragma unroll
            for (int c = 0; c < P + 2; ++c) {
                if (c == 0 && !leftv) continue;       // compile-time c -> uniform guard
                if (c == P + 1 && !rightv) continue;
                u64 v = sh[rr][c][w];
#pragma unroll
                for (int r = 0; r < R; ++r) {
                    constexpr int unused = 0; (void)unused;
                    int dy = rr - r;
                    if (dy < 0 || dy > 2) continue;   // compile-time collapse
                    if (c < P)            acc[r][c]     += __popcll(v ^ wt[dy * 3 + 0]);
                    if (c >= 1 && c <= P) acc[r][c - 1] += __popcll(v ^ wt[dy * 3 + 1]);
                    if (c >= 2)           acc[r][c - 2] += __popcll(v ^ wt[dy * 3 + 2]);
                }
            }
        }
    }

    int lane = tid & 63, wv = tid >> 6;

    if constexpr (OUTF64) {
        double g  = (double)bn[co];
        double be = (double)bn[COUT + co];
        double mu = (double)bn[2 * COUT + co];
        double va = (double)bn[3 * COUT + co];
        double rsq = 1.0 / sqrt(va + 1e-3);
#pragma unroll
        for (int r = 0; r < R; ++r) {
            int yy = y0 + r;
            int ndy = 3 - (yy == 0) - (yy == H - 1);
#pragma unroll
            for (int p = 0; p < P; ++p) {
                int x = x0 + p;
                bool eL = (x == 0), eR = (x == W - 1);
                int nvp = ndy * (3 - eL - eR);
                int y = nvp * (CINW * 64) - 2 * acc[r][p];  // exact integer conv result
                int yr = y > 0 ? y : 0;                      // relu
                double v = g * ((double)yr - mu) * rsq + be; // full BN in f64 (feeds GAP)
                of64[((size_t)(n * H + yy) * W + x) * COUT + co] = v;
            }
        }
    } else {
        double thr = thrd[co];
        bool spos = (sflag[co] != 0);
#pragma unroll
        for (int r = 0; r < R; ++r) {
            int yy = y0 + r;
            int ndy = 3 - (yy == 0) - (yy == H - 1);
#pragma unroll
            for (int p = 0; p < P; ++p) {
                int x = x0 + p;
                bool eL = (x == 0), eR = (x == W - 1);
                int nvp = ndy * (3 - eL - eR);
                int y = nvp * (CINW * 64) - 2 * acc[r][p];  // exact integer conv result
                int yr = y > 0 ? y : 0;                      // relu
                double yd = (double)yr;                      // exact conversion
                bool pred = spos ? (yd >= thr) : (yd <= thr);
                u64 word = __ballot(pred);
                if (lane == 0)
                    obits[((size_t)(n * H + yy) * W + x) * CW + wv] = word;
            }
        }
    }
}

// ---------------- 2x2 maxpool on sign bits = word OR ----------------
__global__ void pool_bits(const u64* __restrict__ in, u64* __restrict__ out,
                          int H2, int W2, int CW) {
    int idx = blockIdx.x * blockDim.x + threadIdx.x;
    int total = 16 * H2 * W2 * CW;
    if (idx >= total) return;
    int wd = idx % CW;
    int rest = idx / CW;
    int px = rest % W2; rest /= W2;
    int py = rest % H2;
    int n = rest / H2;
    int W = 2 * W2;
    const u64* base = in + ((size_t)(n * 2 * H2 + 2 * py) * W + 2 * px) * CW + wd;
    out[idx] = base[0] | base[CW] | base[(size_t)W * CW] | base[(size_t)W * CW + CW];
}

// ---------------- maxpool(14->7) + GAP, split for parallelism (R15-verified) ----------------
__global__ void gap_part(const double* __restrict__ x, double* __restrict__ part) {
    int b = blockIdx.x;            // 16*7
    int py = b % 7, n = b / 7;
    int co = threadIdx.x;          // 512
    double sum = 0.0;
    for (int px = 0; px < 7; ++px) {
        const double* bp = x + ((size_t)(n * 14 + 2 * py) * 14 + 2 * px) * 512 + co;
        double m = bp[0];
        m = fmax(m, bp[512]);
        m = fmax(m, bp[14 * 512]);
        m = fmax(m, bp[14 * 512 + 512]);
        sum += m;
    }
    part[((size_t)n * 7 + py) * 512 + co] = sum;
}

__global__ void gap_final(const double* __restrict__ part, u64* __restrict__ gb) {
    int n = blockIdx.x;
    int co = threadIdx.x;          // 512
    double sum = 0.0;
    for (int py = 0; py < 7; ++py) sum += part[((size_t)n * 7 + py) * 512 + co];
    double mean = sum / 49.0;
    bool pred = (mean >= 0.0);
    u64 word = __ballot(pred);
    if ((co & 63) == 0) gb[n * 8 + (co >> 6)] = word;
}

// ---------------- binary dense: out = 512 - 2*popc ----------------
__global__ void dense_bin(const u64* __restrict__ gb, const u64* __restrict__ dwb,
                          float* __restrict__ out) {
    int idx = blockIdx.x * blockDim.x + threadIdx.x;
    if (idx >= 16000) return;
    int j = idx % 1000, n = idx / 1000;
    const u64* g = gb + n * 8;
    const u64* w = dwb + j * 8;
    int acc = 0;
#pragma unroll
    for (int wd = 0; wd < 8; ++wd) acc += __popcll(g[wd] ^ w[wd]);
    out[idx] = (float)(512 - 2 * acc);
}

extern "C" void kernel_launch(void* const* d_in, const int* in_sizes, int n_in,
                              void* d_out, int out_size, void* d_ws, size_t ws_size,
                              hipStream_t stream) {
    const float* inputs = (const float*)d_in[0];
    const float* w1  = (const float*)d_in[1];
    const float* b1  = (const float*)d_in[2];
    const float* bn1 = (const float*)d_in[3];
    const float* w2  = (const float*)d_in[4];
    const float* bn2 = (const float*)d_in[5];
    const float* w3  = (const float*)d_in[6];
    const float* bn3 = (const float*)d_in[7];
    const float* w4  = (const float*)d_in[8];
    const float* bn4 = (const float*)d_in[9];
    const float* w5  = (const float*)d_in[10];
    const float* bn5 = (const float*)d_in[11];
    const float* w6  = (const float*)d_in[12];
    const float* bn6 = (const float*)d_in[13];
    const float* w7  = (const float*)d_in[14];
    const float* bn7 = (const float*)d_in[15];
    const float* w8  = (const float*)d_in[16];
    const float* bn8 = (const float*)d_in[17];
    const float* dw  = (const float*)d_in[18];
    float* out = (float*)d_out;

    u64* ws = (u64*)d_ws;
    size_t o = 0;
    auto alloc = [&](size_t n) { u64* p = ws + o; o += n; return p; };

    u64* wb2 = alloc(9 * 1 * 128);
    u64* wb3 = alloc(9 * 2 * 256);
    u64* wb4 = alloc(9 * 4 * 256);
    u64* wb5 = alloc(9 * 4 * 512);
    u64* wb6 = alloc(9 * 8 * 512);
    u64* wb7 = alloc(9 * 8 * 512);
    u64* wb8 = alloc(9 * 8 * 512);
    u64* dwb = alloc(1000 * 8);

    double* th1 = (double*)alloc(64);   int* sf1 = (int*)alloc(64);
    double* th2 = (double*)alloc(128);  int* sf2 = (int*)alloc(128);
    double* th3 = (double*)alloc(256);  int* sf3 = (int*)alloc(256);
    double* th4 = (double*)alloc(256);  int* sf4 = (int*)alloc(256);
    double* th5 = (double*)alloc(512);  int* sf5 = (int*)alloc(512);
    double* th6 = (double*)alloc(512);  int* sf6 = (int*)alloc(512);
    double* th7 = (double*)alloc(512);  int* sf7 = (int*)alloc(512);
    float*  tf1 = (float*)alloc(64);

    u64* x2b = alloc(16 * 112 * 112 * 1);
    u64* c2b = alloc(16 * 112 * 112 * 2);
    u64* x3b = alloc(16 * 56 * 56 * 2);
    u64* c3b = alloc(16 * 56 * 56 * 4);
    u64* c4b = alloc(16 * 56 * 56 * 4);
    u64* x5b = alloc(16 * 28 * 28 * 4);
    u64* c5b = alloc(16 * 28 * 28 * 8);
    u64* c6b = alloc(16 * 28 * 28 * 8);
    u64* x7b = alloc(16 * 14 * 14 * 8);
    u64* c7b = alloc(16 * 14 * 14 * 8);
    u64* gb  = alloc(16 * 8);
    double* c8f   = (double*)alloc(16 * 14 * 14 * 512);
    double* gpart = (double*)alloc(16 * 7 * 512);

    auto grid = [](int n, int b) { return (n + b - 1) / b; };
    pack_conv_weights<<<grid(9 * 1 * 128, 256), 256, 0, stream>>>(w2, wb2, 64, 128);
    pack_conv_weights<<<grid(9 * 2 * 256, 256), 256, 0, stream>>>(w3, wb3, 128, 256);
    pack_conv_weights<<<grid(9 * 4 * 256, 256), 256, 0, stream>>>(w4, wb4, 256, 256);
    pack_conv_weights<<<grid(9 * 4 * 512, 256), 256, 0, stream>>>(w5, wb5, 256, 512);
    pack_conv_weights<<<grid(9 * 8 * 512, 256), 256, 0, stream>>>(w6, wb6, 512, 512);
    pack_conv_weights<<<grid(9 * 8 * 512, 256), 256, 0, stream>>>(w7, wb7, 512, 512);
    pack_conv_weights<<<grid(9 * 8 * 512, 256), 256, 0, stream>>>(w8, wb8, 512, 512);
    pack_dense_weights<<<4, 256, 0, stream>>>(dw, dwb);

    prep_bnthr<<<1, 64, 0, stream>>>(bn1, 64, th1, sf1);
    prep_bnthr<<<1, 128, 0, stream>>>(bn2, 128, th2, sf2);
    prep_bnthr<<<1, 256, 0, stream>>>(bn3, 256, th3, sf3);
    prep_bnthr<<<1, 256, 0, stream>>>(bn4, 256, th4, sf4);
    prep_bnthr<<<grid(512, 256), 256, 0, stream>>>(bn5, 512, th5, sf5);
    prep_bnthr<<<grid(512, 256), 256, 0, stream>>>(bn6, 512, th6, sf6);
    prep_bnthr<<<grid(512, 256), 256, 0, stream>>>(bn7, 512, th7, sf7);
    prep_thrf<<<1, 64, 0, stream>>>(th1, tf1);

    conv1_fused<<<16 * 112 * 28 / 4, 256, 0, stream>>>(inputs, w1, b1, tf1, th1, sf1, x2b);

    // R=2 rows per block; W/P and H/R divide exactly at every stage.
    bconv<1, 128, 8, 2, false><<<16 * 56 * 14, 128, 0, stream>>>(x2b, wb2, bn2, th2, sf2, c2b, nullptr, 112, 112);
    pool_bits<<<grid(16 * 56 * 56 * 2, 256), 256, 0, stream>>>(c2b, x3b, 56, 56, 2);
    bconv<2, 256, 8, 2, false><<<16 * 28 * 7, 256, 0, stream>>>(x3b, wb3, bn3, th3, sf3, c3b, nullptr, 56, 56);
    bconv<4, 256, 8, 2, false><<<16 * 28 * 7, 256, 0, stream>>>(c3b, wb4, bn4, th4, sf4, c4b, nullptr, 56, 56);
    pool_bits<<<grid(16 * 28 * 28 * 4, 256), 256, 0, stream>>>(c4b, x5b, 28, 28, 4);
    bconv<4, 512, 7, 2, false><<<16 * 14 * 4, 512, 0, stream>>>(x5b, wb5, bn5, th5, sf5, c5b, nullptr, 28, 28);
    bconv<8, 512, 7, 2, false><<<16 * 14 * 4, 512, 0, stream>>>(c5b, wb6, bn6, th6, sf6, c6b, nullptr, 28, 28);
    pool_bits<<<grid(16 * 14 * 14 * 8, 256), 256, 0, stream>>>(c6b, x7b, 14, 14, 8);
    bconv<8, 512, 7, 2, false><<<16 * 7 * 2, 512, 0, stream>>>(x7b, wb7, bn7, th7, sf7, c7b, nullptr, 14, 14);
    bconv<8, 512, 7, 2, true><<<16 * 7 * 2, 512, 0, stream>>>(c7b, wb8, bn8, nullptr, nullptr, nullptr, c8f, 14, 14);

    gap_part<<<16 * 7, 512, 0, stream>>>(c8f, gpart);
    gap_final<<<16, 512, 0, stream>>>(gpart, gb);
    dense_bin<<<grid(16000, 256), 256, 0, stream>>>(gb, dwb, out);
}

// Round 17
// 519.914 us; speedup vs baseline: 1.0299x; 1.0299x over previous
//
#include <hip/hip_runtime.h>
#include <cstdint>

using u64 = unsigned long long;

// ---------------- weight bit-packing ----------------
__global__ void pack_conv_weights(const float* __restrict__ w, u64* __restrict__ wb,
                                  int Cin, int Cout) {
    int cinw = Cin >> 6;
    int total = 9 * cinw * Cout;
    int idx = blockIdx.x * blockDim.x + threadIdx.x;
    if (idx >= total) return;
    int co = idx % Cout;
    int rest = idx / Cout;
    int wd = rest % cinw;
    int t = rest / cinw;
    u64 word = 0ull;
    for (int b = 0; b < 64; ++b) {
        int ci = (wd << 6) + b;
        float v = w[(t * Cin + ci) * Cout + co];
        if (v >= 0.f) word |= (1ull << b);
    }
    wb[idx] = word;
}

__global__ void pack_dense_weights(const float* __restrict__ w, u64* __restrict__ wb) {
    int j = blockIdx.x * blockDim.x + threadIdx.x;
    if (j >= 1000) return;
    for (int wd = 0; wd < 8; ++wd) {
        u64 word = 0ull;
        for (int b = 0; b < 64; ++b) {
            float v = w[((wd << 6) + b) * 1000 + j];
            if (v >= 0.f) word |= (1ull << b);
        }
        wb[j * 8 + wd] = word;
    }
}

// ---------------- per-channel BN sign thresholds (f64, computed once) ----------------
// v >= 0  <=>  (s>=0 ? r >= thr : r <= thr), s = g*rsqrt(var+eps), thr = mu - be/s
__global__ void prep_bnthr(const float* __restrict__ bn, int cout,
                           double* __restrict__ thrd, int* __restrict__ sflag) {
    int i = blockIdx.x * blockDim.x + threadIdx.x;
    if (i >= cout) return;
    double g  = (double)bn[i];
    double be = (double)bn[cout + i];
    double mu = (double)bn[2 * cout + i];
    double va = (double)bn[3 * cout + i];
    double s  = g * (1.0 / sqrt(va + 1e-3));
    thrd[i] = mu - be / s;
    sflag[i] = (s >= 0.0) ? 1 : 0;
}

__global__ void prep_thrf(const double* __restrict__ thrd, float* __restrict__ thrf) {
    int i = threadIdx.x;
    if (i < 64) thrf[i] = (float)thrd[i];
}

// ---------------- stage 1: fp conv 3->64 + bias + relu + BN + maxpool + sign ----------------
// R14-verified structure: one wave x 4 pooled pixels; per-pixel 4x4x3 patch in registers;
// f32 main path vs precomputed threshold; f64 fixup only in |rf-thr|<TAU band.
// TAU=1e-4: worst-case f32 accum error bound ~5.7e-5 (28 fmas, |partial|<=34, 2^-24)
// -> >=1.75x margin, half the band hits of TAU=2e-4.
// launch_bounds(256,1): VGPR ~104, no spill. (256,4) would cap VGPR at 64 -> spill (R7).
__global__ __launch_bounds__(256, 1)
void conv1_fused(const float* __restrict__ in, const float* __restrict__ w,
                 const float* __restrict__ bias,
                 const float* __restrict__ thrf, const double* __restrict__ thrd,
                 const int* __restrict__ sflag,
                 u64* __restrict__ outbits) {
    int lane = threadIdx.x & 63;
    int wid = blockIdx.x * (blockDim.x >> 6) + (threadIdx.x >> 6);  // 16*112*28 waves
    int pxq = wid % 28;
    int py  = (wid / 28) % 112;
    int n   = wid / (28 * 112);

    float  thrv = thrf[lane];
    double thrD = thrd[lane];
    bool   spos = (sflag[lane] != 0);
    float  bif  = bias[lane];

    float wreg[27];
#pragma unroll
    for (int t = 0; t < 9; ++t)
#pragma unroll
        for (int c = 0; c < 3; ++c)
            wreg[t * 3 + c] = w[(t * 3 + c) * 64 + lane];

    const float TAU = 1e-4f;
    int iy0 = 2 * py - 1;
    bool rowint = (py >= 1) & (py <= 110);

#pragma unroll 1
    for (int pp = 0; pp < 4; ++pp) {
        int px = 4 * pxq + pp;
        int ix0 = 2 * px - 1;

        float patch[4][12];
        bool interior = rowint & (px >= 1) & (px <= 110);
        if (interior) {
            const float* base = in + ((size_t)(n * 224 + iy0) * 224 + ix0) * 3;
#pragma unroll
            for (int r = 0; r < 4; ++r) {
                const float* rp = base + (size_t)r * (224 * 3);
#pragma unroll
                for (int c = 0; c < 12; ++c) patch[r][c] = rp[c];
            }
        } else {
#pragma unroll
            for (int r = 0; r < 4; ++r) {
                int iy = iy0 + r;
                bool rv = (iy >= 0) & (iy < 224);
#pragma unroll
                for (int cc = 0; cc < 4; ++cc) {
                    int ix = ix0 + cc;
                    bool v = rv & (ix >= 0) & (ix < 224);
                    const float* p = in + ((size_t)(n * 224 + iy) * 224 + ix) * 3;
#pragma unroll
                    for (int c = 0; c < 3; ++c)
                        patch[r][cc * 3 + c] = v ? p[c] : 0.f;
                }
            }
        }

        bool pred = false;
#pragma unroll
        for (int q = 0; q < 4; ++q) {
            int qy = q >> 1, qx = q & 1;
            float accf = bif;
#pragma unroll
            for (int dy = 0; dy < 3; ++dy)
#pragma unroll
                for (int dx = 0; dx < 3; ++dx)
#pragma unroll
                    for (int c = 0; c < 3; ++c)
                        accf = fmaf(patch[qy + dy][(qx + dx) * 3 + c],
                                    wreg[(dy * 3 + dx) * 3 + c], accf);
            float rf = fmaxf(accf, 0.f);
            bool p = spos ? (rf >= thrv) : (rf <= thrv);
            if (fabsf(rf - thrv) < TAU) {
                double acc = (double)bif;
#pragma unroll
                for (int dy = 0; dy < 3; ++dy)
#pragma unroll
                    for (int dx = 0; dx < 3; ++dx)
#pragma unroll
                        for (int c = 0; c < 3; ++c)
                            acc = fma((double)patch[qy + dy][(qx + dx) * 3 + c],
                                      (double)wreg[(dy * 3 + dx) * 3 + c], acc);
                double rd = fmax(acc, 0.0);
                p = spos ? (rd >= thrD) : (rd <= thrD);
            }
            pred |= p;                    // sign(max) = max(sign) -> OR over 2x2 pool
        }
        u64 word = __ballot(pred);
        if (lane == 0) outbits[((size_t)(n * 112 + py)) * 112 + px] = word;
    }
}

// ---------------- generic binary conv + relu + BN + sign (R15-verbatim, best-known) ----------------
// Sliding-window inner loop: each LDS word sh[dy][c][w] is read ONCE and applied to the
// <=3 pixels it serves. Only w0,w1,w2 + v live per iteration — no spill (R10 lesson).
// Border columns skipped via wave-uniform guards; nvp = ndy*(3-eL-eR) closed form.
// NO launch_bounds (R7/R10: explicit bounds here backfire).
template<int CINW, int COUT, int P, bool OUTF64>
__global__ void bconv(const u64* __restrict__ xin, const u64* __restrict__ wb,
                      const float* __restrict__ bn,
                      const double* __restrict__ thrd, const int* __restrict__ sflag,
                      u64* __restrict__ obits, double* __restrict__ of64,
                      int H, int W) {
    constexpr int CW = COUT >> 6;
    __shared__ u64 sh[3][P + 2][CINW];

    int tid = threadIdx.x;  // = co
    int XT = (W + P - 1) / P;
    int pos = blockIdx.x;
    int xt = pos % XT;
    int yy = (pos / XT) % H;
    int n  = pos / (XT * H);
    int x0 = xt * P;

    for (int i = tid; i < 3 * (P + 2) * CINW; i += COUT) {
        int wd = i % CINW;
        int cc = (i / CINW) % (P + 2);
        int rr = i / (CINW * (P + 2));
        int gy = yy - 1 + rr, gx = x0 - 1 + cc;
        u64 v = 0ull;
        if (gy >= 0 && gy < H && gx >= 0 && gx < W)
            v = xin[((size_t)(n * H + gy) * W + gx) * CINW + wd];
        sh[rr][cc][wd] = v;
    }
    __syncthreads();

    int acc[P];
#pragma unroll
    for (int p = 0; p < P; ++p) acc[p] = 0;

    int co = tid;
    bool leftv  = (x0 > 0);        // column c=0   (gx = x0-1) valid?
    bool rightv = (x0 + P < W);    // column c=P+1 (gx = x0+P) valid?

    for (int dy = 0; dy < 3; ++dy) {
        int gy = yy - 1 + dy;
        if (gy < 0 || gy >= H) continue;  // uniform across block
#pragma unroll 1
        for (int w = 0; w < CINW; ++w) {
            u64 w0 = wb[((dy * 3 + 0) * CINW + w) * COUT + co];
            u64 w1 = wb[((dy * 3 + 1) * CINW + w) * COUT + co];
            u64 w2 = wb[((dy * 3 + 2) * CINW + w) * COUT + co];
#pragma unroll
            for (int c = 0; c < P + 2; ++c) {
                if (c == 0 && !leftv) continue;       // compile-time c -> uniform guard
                if (c == P + 1 && !rightv) continue;
                u64 v = sh[dy][c][w];
                if (c < P)  acc[c]     += __popcll(v ^ w0);   // dx=0 serves pixel c
                if (c >= 1 && c <= P) acc[c - 1] += __popcll(v ^ w1);   // dx=1
                if (c >= 2) acc[c - 2] += __popcll(v ^ w2);   // dx=2 (c-2 < P always)
            }
        }
    }

    int ndy = 3 - (yy == 0) - (yy == H - 1);
    int lane = tid & 63, wv = tid >> 6;

    if constexpr (OUTF64) {
        double g  = (double)bn[co];
        double be = (double)bn[COUT + co];
        double mu = (double)bn[2 * COUT + co];
        double va = (double)bn[3 * COUT + co];
        double rsq = 1.0 / sqrt(va + 1e-3);
#pragma unroll
        for (int p = 0; p < P; ++p) {
            int x = x0 + p;
            bool eL = (x == 0), eR = (x == W - 1);
            int nvp = ndy * (3 - eL - eR);
            int y = nvp * (CINW * 64) - 2 * acc[p];     // exact integer conv result
            int yr = y > 0 ? y : 0;                      // relu
            double v = g * ((double)yr - mu) * rsq + be; // full BN in f64 (feeds GAP)
            if (x < W) of64[((size_t)(n * H + yy) * W + x) * COUT + co] = v;
        }
    } else {
        double thr = thrd[co];
        bool spos = (sflag[co] != 0);
#pragma unroll
        for (int p = 0; p < P; ++p) {
            int x = x0 + p;
            bool eL = (x == 0), eR = (x == W - 1);
            int nvp = ndy * (3 - eL - eR);
            int y = nvp * (CINW * 64) - 2 * acc[p];     // exact integer conv result
            int yr = y > 0 ? y : 0;                      // relu
            double yd = (double)yr;                      // exact conversion
            bool pred = spos ? (yd >= thr) : (yd <= thr);
            u64 word = __ballot(pred);
            if (lane == 0 && x < W)
                obits[((size_t)(n * H + yy) * W + x) * CW + wv] = word;
        }
    }
}

// ---------------- 2x2 maxpool on sign bits = word OR ----------------
__global__ void pool_bits(const u64* __restrict__ in, u64* __restrict__ out,
                          int H2, int W2, int CW) {
    int idx = blockIdx.x * blockDim.x + threadIdx.x;
    int total = 16 * H2 * W2 * CW;
    if (idx >= total) return;
    int wd = idx % CW;
    int rest = idx / CW;
    int px = rest % W2; rest /= W2;
    int py = rest % H2;
    int n = rest / H2;
    int W = 2 * W2;
    const u64* base = in + ((size_t)(n * 2 * H2 + 2 * py) * W + 2 * px) * CW + wd;
    out[idx] = base[0] | base[CW] | base[(size_t)W * CW] | base[(size_t)W * CW + CW];
}

// ---------------- maxpool(14->7) + GAP, split for parallelism (R15-verified) ----------------
__global__ void gap_part(const double* __restrict__ x, double* __restrict__ part) {
    int b = blockIdx.x;            // 16*7
    int py = b % 7, n = b / 7;
    int co = threadIdx.x;          // 512
    double sum = 0.0;
    for (int px = 0; px < 7; ++px) {
        const double* bp = x + ((size_t)(n * 14 + 2 * py) * 14 + 2 * px) * 512 + co;
        double m = bp[0];
        m = fmax(m, bp[512]);
        m = fmax(m, bp[14 * 512]);
        m = fmax(m, bp[14 * 512 + 512]);
        sum += m;
    }
    part[((size_t)n * 7 + py) * 512 + co] = sum;
}

__global__ void gap_final(const double* __restrict__ part, u64* __restrict__ gb) {
    int n = blockIdx.x;
    int co = threadIdx.x;          // 512
    double sum = 0.0;
    for (int py = 0; py < 7; ++py) sum += part[((size_t)n * 7 + py) * 512 + co];
    double mean = sum / 49.0;
    bool pred = (mean >= 0.0);
    u64 word = __ballot(pred);
    if ((co & 63) == 0) gb[n * 8 + (co >> 6)] = word;
}

// ---------------- binary dense: out = 512 - 2*popc ----------------
__global__ void dense_bin(const u64* __restrict__ gb, const u64* __restrict__ dwb,
                          float* __restrict__ out) {
    int idx = blockIdx.x * blockDim.x + threadIdx.x;
    if (idx >= 16000) return;
    int j = idx % 1000, n = idx / 1000;
    const u64* g = gb + n * 8;
    const u64* w = dwb + j * 8;
    int acc = 0;
#pragma unroll
    for (int wd = 0; wd < 8; ++wd) acc += __popcll(g[wd] ^ w[wd]);
    out[idx] = (float)(512 - 2 * acc);
}

extern "C" void kernel_launch(void* const* d_in, const int* in_sizes, int n_in,
                              void* d_out, int out_size, void* d_ws, size_t ws_size,
                              hipStream_t stream) {
    const float* inputs = (const float*)d_in[0];
    const float* w1  = (const float*)d_in[1];
    const float* b1  = (const float*)d_in[2];
    const float* bn1 = (const float*)d_in[3];
    const float* w2  = (const float*)d_in[4];
    const float* bn2 = (const float*)d_in[5];
    const float* w3  = (const float*)d_in[6];
    const float* bn3 = (const float*)d_in[7];
    const float* w4  = (const float*)d_in[8];
    const float* bn4 = (const float*)d_in[9];
    const float* w5  = (const float*)d_in[10];
    const float* bn5 = (const float*)d_in[11];
    const float* w6  = (const float*)d_in[12];
    const float* bn6 = (const float*)d_in[13];
    const float* w7  = (const float*)d_in[14];
    const float* bn7 = (const float*)d_in[15];
    const float* w8  = (const float*)d_in[16];
    const float* bn8 = (const float*)d_in[17];
    const float* dw  = (const float*)d_in[18];
    float* out = (float*)d_out;

    u64* ws = (u64*)d_ws;
    size_t o = 0;
    auto alloc = [&](size_t n) { u64* p = ws + o; o += n; return p; };

    u64* wb2 = alloc(9 * 1 * 128);
    u64* wb3 = alloc(9 * 2 * 256);
    u64* wb4 = alloc(9 * 4 * 256);
    u64* wb5 = alloc(9 * 4 * 512);
    u64* wb6 = alloc(9 * 8 * 512);
    u64* wb7 = alloc(9 * 8 * 512);
    u64* wb8 = alloc(9 * 8 * 512);
    u64* dwb = alloc(1000 * 8);

    double* th1 = (double*)alloc(64);   int* sf1 = (int*)alloc(64);
    double* th2 = (double*)alloc(128);  int* sf2 = (int*)alloc(128);
    double* th3 = (double*)alloc(256);  int* sf3 = (int*)alloc(256);
    double* th4 = (double*)alloc(256);  int* sf4 = (int*)alloc(256);
    double* th5 = (double*)alloc(512);  int* sf5 = (int*)alloc(512);
    double* th6 = (double*)alloc(512);  int* sf6 = (int*)alloc(512);
    double* th7 = (double*)alloc(512);  int* sf7 = (int*)alloc(512);
    float*  tf1 = (float*)alloc(64);

    u64* x2b = alloc(16 * 112 * 112 * 1);
    u64* c2b = alloc(16 * 112 * 112 * 2);
    u64* x3b = alloc(16 * 56 * 56 * 2);
    u64* c3b = alloc(16 * 56 * 56 * 4);
    u64* c4b = alloc(16 * 56 * 56 * 4);
    u64* x5b = alloc(16 * 28 * 28 * 4);
    u64* c5b = alloc(16 * 28 * 28 * 8);
    u64* c6b = alloc(16 * 28 * 28 * 8);
    u64* x7b = alloc(16 * 14 * 14 * 8);
    u64* c7b = alloc(16 * 14 * 14 * 8);
    u64* gb  = alloc(16 * 8);
    double* c8f   = (double*)alloc(16 * 14 * 14 * 512);
    double* gpart = (double*)alloc(16 * 7 * 512);

    auto grid = [](int n, int b) { return (n + b - 1) / b; };
    pack_conv_weights<<<grid(9 * 1 * 128, 256), 256, 0, stream>>>(w2, wb2, 64, 128);
    pack_conv_weights<<<grid(9 * 2 * 256, 256), 256, 0, stream>>>(w3, wb3, 128, 256);
    pack_conv_weights<<<grid(9 * 4 * 256, 256), 256, 0, stream>>>(w4, wb4, 256, 256);
    pack_conv_weights<<<grid(9 * 4 * 512, 256), 256, 0, stream>>>(w5, wb5, 256, 512);
    pack_conv_weights<<<grid(9 * 8 * 512, 256), 256, 0, stream>>>(w6, wb6, 512, 512);
    pack_conv_weights<<<grid(9 * 8 * 512, 256), 256, 0, stream>>>(w7, wb7, 512, 512);
    pack_conv_weights<<<grid(9 * 8 * 512, 256), 256, 0, stream>>>(w8, wb8, 512, 512);
    pack_dense_weights<<<4, 256, 0, stream>>>(dw, dwb);

    prep_bnthr<<<1, 64, 0, stream>>>(bn1, 64, th1, sf1);
    prep_bnthr<<<1, 128, 0, stream>>>(bn2, 128, th2, sf2);
    prep_bnthr<<<1, 256, 0, stream>>>(bn3, 256, th3, sf3);
    prep_bnthr<<<1, 256, 0, stream>>>(bn4, 256, th4, sf4);
    prep_bnthr<<<grid(512, 256), 256, 0, stream>>>(bn5, 512, th5, sf5);
    prep_bnthr<<<grid(512, 256), 256, 0, stream>>>(bn6, 512, th6, sf6);
    prep_bnthr<<<grid(512, 256), 256, 0, stream>>>(bn7, 512, th7, sf7);
    prep_thrf<<<1, 64, 0, stream>>>(th1, tf1);

    conv1_fused<<<16 * 112 * 28 / 4, 256, 0, stream>>>(inputs, w1, b1, tf1, th1, sf1, x2b);

    bconv<1, 128, 8, false><<<16 * 112 * 14, 128, 0, stream>>>(x2b, wb2, bn2, th2, sf2, c2b, nullptr, 112, 112);
    pool_bits<<<grid(16 * 56 * 56 * 2, 256), 256, 0, stream>>>(c2b, x3b, 56, 56, 2);
    bconv<2, 256, 8, false><<<16 * 56 * 7, 256, 0, stream>>>(x3b, wb3, bn3, th3, sf3, c3b, nullptr, 56, 56);
    bconv<4, 256, 8, false><<<16 * 56 * 7, 256, 0, stream>>>(c3b, wb4, bn4, th4, sf4, c4b, nullptr, 56, 56);
    pool_bits<<<grid(16 * 28 * 28 * 4, 256), 256, 0, stream>>>(c4b, x5b, 28, 28, 4);
    bconv<4, 512, 7, false><<<16 * 28 * 4, 512, 0, stream>>>(x5b, wb5, bn5, th5, sf5, c5b, nullptr, 28, 28);
    bconv<8, 512, 7, false><<<16 * 28 * 4, 512, 0, stream>>>(c5b, wb6, bn6, th6, sf6, c6b, nullptr, 28, 28);
    pool_bits<<<grid(16 * 14 * 14 * 8, 256), 256, 0, stream>>>(c6b, x7b, 14, 14, 8);
    bconv<8, 512, 7, false><<<16 * 14 * 2, 512, 0, stream>>>(x7b, wb7, bn7, th7, sf7, c7b, nullptr, 14, 14);
    bconv<8, 512, 7, true><<<16 * 14 * 2, 512, 0, stream>>>(c7b, wb8, bn8, nullptr, nullptr, nullptr, c8f, 14, 14);

    gap_part<<<16 * 7, 512, 0, stream>>>(c8f, gpart);
    gap_final<<<16, 512, 0, stream>>>(gpart, gb);
    dense_bin<<<grid(16000, 256), 256, 0, stream>>>(gb, dwb, out);
}

// Round 18
// 473.131 us; speedup vs baseline: 1.1318x; 1.0989x over previous
//
#include <hip/hip_runtime.h>
#include <cstdint>

using u64 = unsigned long long;

typedef float f32x4 __attribute__((ext_vector_type(4)));
typedef f32x4 f32x4u __attribute__((aligned(4)));   // 4B-aligned vector load (gfx950 HW ok)

// ---------------- fused weight bit-packing (7 conv layers + dense in ONE launch) ----------------
struct PackDesc {
    const float* w[7];
    u64*         wb[7];
    int cinw[7];
    int cout[7];
    int start[8];      // prefix offsets in words
};

__global__ void pack_all(PackDesc d, const float* __restrict__ dw, u64* __restrict__ dwb) {
    int idx = blockIdx.x * blockDim.x + threadIdx.x;
    int total = d.start[7];
    if (idx < total) {
        int L = 0;
        while (idx >= d.start[L + 1]) ++L;
        int r = idx - d.start[L];
        int cout = d.cout[L], cinw = d.cinw[L];
        int co = r % cout;
        int rest = r / cout;
        int wd = rest % cinw;
        int t  = rest / cinw;
        int Cin = cinw << 6;
        const float* w = d.w[L];
        u64 word = 0ull;
        for (int b = 0; b < 64; ++b) {
            float v = w[((size_t)(t * Cin + (wd << 6) + b)) * cout + co];
            if (v >= 0.f) word |= (1ull << b);
        }
        d.wb[L][r] = word;
    } else if (idx < total + 1000) {
        int j = idx - total;
        for (int wd = 0; wd < 8; ++wd) {
            u64 word = 0ull;
            for (int b = 0; b < 64; ++b) {
                float v = dw[((wd << 6) + b) * 1000 + j];
                if (v >= 0.f) word |= (1ull << b);
            }
            dwb[j * 8 + wd] = word;
        }
    }
}

// ---------------- fused BN threshold prep (7 layers in ONE launch) ----------------
// v >= 0  <=>  (s>=0 ? r >= thr : r <= thr), s = g*rsqrt(var+eps), thr = mu - be/s
struct PrepDesc {
    const float* bn[7];
    double*      thrd[7];
    int*         sflag[7];
    int cout[7];
    int start[8];
};

__global__ void prep_all(PrepDesc d, float* __restrict__ tf1) {
    int idx = blockIdx.x * blockDim.x + threadIdx.x;
    if (idx >= d.start[7]) return;
    int L = 0;
    while (idx >= d.start[L + 1]) ++L;
    int i = idx - d.start[L];
    int cout = d.cout[L];
    const float* bn = d.bn[L];
    double g  = (double)bn[i];
    double be = (double)bn[cout + i];
    double mu = (double)bn[2 * cout + i];
    double va = (double)bn[3 * cout + i];
    double s  = g * (1.0 / sqrt(va + 1e-3));
    double thr = mu - be / s;
    d.thrd[L][i] = thr;
    d.sflag[L][i] = (s >= 0.0) ? 1 : 0;
    if (L == 0) tf1[i] = (float)thr;   // conv1 f32 threshold
}

// ---------------- stage 1: fp conv 3->64 + bias + relu + BN + maxpool + sign ----------------
// R14-verified structure + vectorized interior loads: each 12-float patch row = 3x
// dwordx4 (4B-aligned vector type) -> interior VMEM 48->12 instrs/pixel (R17 analysis:
// conv1 was VMEM-issue/latency-co-bound at 52% VALUBusy, 20% occupancy).
// f32 main path vs precomputed threshold; f64 fixup only in |rf-thr|<TAU band.
// launch_bounds(256,1): VGPR ~104, no spill. (256,4) caps VGPR at 64 -> spill (R7).
__global__ __launch_bounds__(256, 1)
void conv1_fused(const float* __restrict__ in, const float* __restrict__ w,
                 const float* __restrict__ bias,
                 const float* __restrict__ thrf, const double* __restrict__ thrd,
                 const int* __restrict__ sflag,
                 u64* __restrict__ outbits) {
    int lane = threadIdx.x & 63;
    int wid = blockIdx.x * (blockDim.x >> 6) + (threadIdx.x >> 6);  // 16*112*28 waves
    int pxq = wid % 28;
    int py  = (wid / 28) % 112;
    int n   = wid / (28 * 112);

    float  thrv = thrf[lane];
    double thrD = thrd[lane];
    bool   spos = (sflag[lane] != 0);
    float  bif  = bias[lane];

    float wreg[27];
#pragma unroll
    for (int t = 0; t < 9; ++t)
#pragma unroll
        for (int c = 0; c < 3; ++c)
            wreg[t * 3 + c] = w[(t * 3 + c) * 64 + lane];

    const float TAU = 1e-4f;
    int iy0 = 2 * py - 1;
    bool rowint = (py >= 1) & (py <= 110);

#pragma unroll 1
    for (int pp = 0; pp < 4; ++pp) {
        int px = 4 * pxq + pp;
        int ix0 = 2 * px - 1;

        f32x4 patch[4][3];                 // 4 rows x 12 floats
        bool interior = rowint & (px >= 1) & (px <= 110);
        if (interior) {
            const float* base = in + ((size_t)(n * 224 + iy0) * 224 + ix0) * 3;
#pragma unroll
            for (int r = 0; r < 4; ++r) {
                const f32x4u* vp = (const f32x4u*)(base + (size_t)r * (224 * 3));
                patch[r][0] = vp[0];
                patch[r][1] = vp[1];
                patch[r][2] = vp[2];
            }
        } else {
#pragma unroll
            for (int r = 0; r < 4; ++r) {
                float* pr = (float*)&patch[r][0];
                int iy = iy0 + r;
                bool rv = (iy >= 0) & (iy < 224);
#pragma unroll
                for (int cc = 0; cc < 4; ++cc) {
                    int ix = ix0 + cc;
                    bool v = rv & (ix >= 0) & (ix < 224);
                    const float* p = in + ((size_t)(n * 224 + iy) * 224 + ix) * 3;
#pragma unroll
                    for (int c = 0; c < 3; ++c)
                        pr[cc * 3 + c] = v ? p[c] : 0.f;
                }
            }
        }

        bool pred = false;
#pragma unroll
        for (int q = 0; q < 4; ++q) {
            int qy = q >> 1, qx = q & 1;
            float accf = bif;
#pragma unroll
            for (int dy = 0; dy < 3; ++dy)
#pragma unroll
                for (int dx = 0; dx < 3; ++dx)
#pragma unroll
                    for (int c = 0; c < 3; ++c) {
                        const int fi = (qx + dx) * 3 + c;
                        accf = fmaf(patch[qy + dy][fi >> 2][fi & 3],
                                    wreg[(dy * 3 + dx) * 3 + c], accf);
                    }
            float rf = fmaxf(accf, 0.f);
            bool p = spos ? (rf >= thrv) : (rf <= thrv);
            if (fabsf(rf - thrv) < TAU) {
                // rare sign-critical band: exact f64 conv + f64 threshold compare
                double acc = (double)bif;
#pragma unroll
                for (int dy = 0; dy < 3; ++dy)
#pragma unroll
                    for (int dx = 0; dx < 3; ++dx)
#pragma unroll
                        for (int c = 0; c < 3; ++c) {
                            const int fi = (qx + dx) * 3 + c;
                            acc = fma((double)patch[qy + dy][fi >> 2][fi & 3],
                                      (double)wreg[(dy * 3 + dx) * 3 + c], acc);
                        }
                double rd = fmax(acc, 0.0);
                p = spos ? (rd >= thrD) : (rd <= thrD);
            }
            pred |= p;                    // sign(max) = max(sign) -> OR over 2x2 pool
        }
        u64 word = __ballot(pred);
        if (lane == 0) outbits[((size_t)(n * 112 + py)) * 112 + px] = word;
    }
}

// ---------------- generic binary conv + relu + BN + sign (R15-verbatim, best-known) ----------------
// Sliding-window inner loop: each LDS word sh[dy][c][w] is read ONCE and applied to the
// <=3 pixels it serves. Only w0,w1,w2 + v live per iteration — no spill (R10 lesson).
// Border columns skipped via wave-uniform guards; nvp = ndy*(3-eL-eR) closed form.
// NO launch_bounds (R7/R10: explicit bounds here backfire).
template<int CINW, int COUT, int P, bool OUTF64>
__global__ void bconv(const u64* __restrict__ xin, const u64* __restrict__ wb,
                      const float* __restrict__ bn,
                      const double* __restrict__ thrd, const int* __restrict__ sflag,
                      u64* __restrict__ obits, double* __restrict__ of64,
                      int H, int W) {
    constexpr int CW = COUT >> 6;
    __shared__ u64 sh[3][P + 2][CINW];

    int tid = threadIdx.x;  // = co
    int XT = (W + P - 1) / P;
    int pos = blockIdx.x;
    int xt = pos % XT;
    int yy = (pos / XT) % H;
    int n  = pos / (XT * H);
    int x0 = xt * P;

    for (int i = tid; i < 3 * (P + 2) * CINW; i += COUT) {
        int wd = i % CINW;
        int cc = (i / CINW) % (P + 2);
        int rr = i / (CINW * (P + 2));
        int gy = yy - 1 + rr, gx = x0 - 1 + cc;
        u64 v = 0ull;
        if (gy >= 0 && gy < H && gx >= 0 && gx < W)
            v = xin[((size_t)(n * H + gy) * W + gx) * CINW + wd];
        sh[rr][cc][wd] = v;
    }
    __syncthreads();

    int acc[P];
#pragma unroll
    for (int p = 0; p < P; ++p) acc[p] = 0;

    int co = tid;
    bool leftv  = (x0 > 0);        // column c=0   (gx = x0-1) valid?
    bool rightv = (x0 + P < W);    // column c=P+1 (gx = x0+P) valid?

    for (int dy = 0; dy < 3; ++dy) {
        int gy = yy - 1 + dy;
        if (gy < 0 || gy >= H) continue;  // uniform across block
#pragma unroll 1
        for (int w = 0; w < CINW; ++w) {
            u64 w0 = wb[((dy * 3 + 0) * CINW + w) * COUT + co];
            u64 w1 = wb[((dy * 3 + 1) * CINW + w) * COUT + co];
            u64 w2 = wb[((dy * 3 + 2) * CINW + w) * COUT + co];
#pragma unroll
            for (int c = 0; c < P + 2; ++c) {
                if (c == 0 && !leftv) continue;       // compile-time c -> uniform guard
                if (c == P + 1 && !rightv) continue;
                u64 v = sh[dy][c][w];
                if (c < P)  acc[c]     += __popcll(v ^ w0);   // dx=0 serves pixel c
                if (c >= 1 && c <= P) acc[c - 1] += __popcll(v ^ w1);   // dx=1
                if (c >= 2) acc[c - 2] += __popcll(v ^ w2);   // dx=2 (c-2 < P always)
            }
        }
    }

    int ndy = 3 - (yy == 0) - (yy == H - 1);
    int lane = tid & 63, wv = tid >> 6;

    if constexpr (OUTF64) {
        double g  = (double)bn[co];
        double be = (double)bn[COUT + co];
        double mu = (double)bn[2 * COUT + co];
        double va = (double)bn[3 * COUT + co];
        double rsq = 1.0 / sqrt(va + 1e-3);
#pragma unroll
        for (int p = 0; p < P; ++p) {
            int x = x0 + p;
            bool eL = (x == 0), eR = (x == W - 1);
            int nvp = ndy * (3 - eL - eR);
            int y = nvp * (CINW * 64) - 2 * acc[p];     // exact integer conv result
            int yr = y > 0 ? y : 0;                      // relu
            double v = g * ((double)yr - mu) * rsq + be; // full BN in f64 (feeds GAP)
            if (x < W) of64[((size_t)(n * H + yy) * W + x) * COUT + co] = v;
        }
    } else {
        double thr = thrd[co];
        bool spos = (sflag[co] != 0);
#pragma unroll
        for (int p = 0; p < P; ++p) {
            int x = x0 + p;
            bool eL = (x == 0), eR = (x == W - 1);
            int nvp = ndy * (3 - eL - eR);
            int y = nvp * (CINW * 64) - 2 * acc[p];     // exact integer conv result
            int yr = y > 0 ? y : 0;                      // relu
            double yd = (double)yr;                      // exact conversion
            bool pred = spos ? (yd >= thr) : (yd <= thr);
            u64 word = __ballot(pred);
            if (lane == 0 && x < W)
                obits[((size_t)(n * H + yy) * W + x) * CW + wv] = word;
        }
    }
}

// ---------------- 2x2 maxpool on sign bits = word OR ----------------
__global__ void pool_bits(const u64* __restrict__ in, u64* __restrict__ out,
                          int H2, int W2, int CW) {
    int idx = blockIdx.x * blockDim.x + threadIdx.x;
    int total = 16 * H2 * W2 * CW;
    if (idx >= total) return;
    int wd = idx % CW;
    int rest = idx / CW;
    int px = rest % W2; rest /= W2;
    int py = rest % H2;
    int n = rest / H2;
    int W = 2 * W2;
    const u64* base = in + ((size_t)(n * 2 * H2 + 2 * py) * W + 2 * px) * CW + wd;
    out[idx] = base[0] | base[CW] | base[(size_t)W * CW] | base[(size_t)W * CW + CW];
}

// ---------------- maxpool(14->7) + GAP, split for parallelism (R15-verified) ----------------
__global__ void gap_part(const double* __restrict__ x, double* __restrict__ part) {
    int b = blockIdx.x;            // 16*7
    int py = b % 7, n = b / 7;
    int co = threadIdx.x;          // 512
    double sum = 0.0;
    for (int px = 0; px < 7; ++px) {
        const double* bp = x + ((size_t)(n * 14 + 2 * py) * 14 + 2 * px) * 512 + co;
        double m = bp[0];
        m = fmax(m, bp[512]);
        m = fmax(m, bp[14 * 512]);
        m = fmax(m, bp[14 * 512 + 512]);
        sum += m;
    }
    part[((size_t)n * 7 + py) * 512 + co] = sum;
}

__global__ void gap_final(const double* __restrict__ part, u64* __restrict__ gb) {
    int n = blockIdx.x;
    int co = threadIdx.x;          // 512
    double sum = 0.0;
    for (int py = 0; py < 7; ++py) sum += part[((size_t)n * 7 + py) * 512 + co];
    double mean = sum / 49.0;
    bool pred = (mean >= 0.0);
    u64 word = __ballot(pred);
    if ((co & 63) == 0) gb[n * 8 + (co >> 6)] = word;
}

// ---------------- binary dense: out = 512 - 2*popc ----------------
__global__ void dense_bin(const u64* __restrict__ gb, const u64* __restrict__ dwb,
                          float* __restrict__ out) {
    int idx = blockIdx.x * blockDim.x + threadIdx.x;
    if (idx >= 16000) return;
    int j = idx % 1000, n = idx / 1000;
    const u64* g = gb + n * 8;
    const u64* w = dwb + j * 8;
    int acc = 0;
#pragma unroll
    for (int wd = 0; wd < 8; ++wd) acc += __popcll(g[wd] ^ w[wd]);
    out[idx] = (float)(512 - 2 * acc);
}

extern "C" void kernel_launch(void* const* d_in, const int* in_sizes, int n_in,
                              void* d_out, int out_size, void* d_ws, size_t ws_size,
                              hipStream_t stream) {
    const float* inputs = (const float*)d_in[0];
    const float* w1  = (const float*)d_in[1];
    const float* b1  = (const float*)d_in[2];
    const float* bn1 = (const float*)d_in[3];
    const float* w2  = (const float*)d_in[4];
    const float* bn2 = (const float*)d_in[5];
    const float* w3  = (const float*)d_in[6];
    const float* bn3 = (const float*)d_in[7];
    const float* w4  = (const float*)d_in[8];
    const float* bn4 = (const float*)d_in[9];
    const float* w5  = (const float*)d_in[10];
    const float* bn5 = (const float*)d_in[11];
    const float* w6  = (const float*)d_in[12];
    const float* bn6 = (const float*)d_in[13];
    const float* w7  = (const float*)d_in[14];
    const float* bn7 = (const float*)d_in[15];
    const float* w8  = (const float*)d_in[16];
    const float* bn8 = (const float*)d_in[17];
    const float* dw  = (const float*)d_in[18];
    float* out = (float*)d_out;

    u64* ws = (u64*)d_ws;
    size_t o = 0;
    auto alloc = [&](size_t n) { u64* p = ws + o; o += n; return p; };

    u64* wb2 = alloc(9 * 1 * 128);
    u64* wb3 = alloc(9 * 2 * 256);
    u64* wb4 = alloc(9 * 4 * 256);
    u64* wb5 = alloc(9 * 4 * 512);
    u64* wb6 = alloc(9 * 8 * 512);
    u64* wb7 = alloc(9 * 8 * 512);
    u64* wb8 = alloc(9 * 8 * 512);
    u64* dwb = alloc(1000 * 8);

    double* th1 = (double*)alloc(64);   int* sf1 = (int*)alloc(64);
    double* th2 = (double*)alloc(128);  int* sf2 = (int*)alloc(128);
    double* th3 = (double*)alloc(256);  int* sf3 = (int*)alloc(256);
    double* th4 = (double*)alloc(256);  int* sf4 = (int*)alloc(256);
    double* th5 = (double*)alloc(512);  int* sf5 = (int*)alloc(512);
    double* th6 = (double*)alloc(512);  int* sf6 = (int*)alloc(512);
    double* th7 = (double*)alloc(512);  int* sf7 = (int*)alloc(512);
    float*  tf1 = (float*)alloc(64);

    u64* x2b = alloc(16 * 112 * 112 * 1);
    u64* c2b = alloc(16 * 112 * 112 * 2);
    u64* x3b = alloc(16 * 56 * 56 * 2);
    u64* c3b = alloc(16 * 56 * 56 * 4);
    u64* c4b = alloc(16 * 56 * 56 * 4);
    u64* x5b = alloc(16 * 28 * 28 * 4);
    u64* c5b = alloc(16 * 28 * 28 * 8);
    u64* c6b = alloc(16 * 28 * 28 * 8);
    u64* x7b = alloc(16 * 14 * 14 * 8);
    u64* c7b = alloc(16 * 14 * 14 * 8);
    u64* gb  = alloc(16 * 8);
    double* c8f   = (double*)alloc(16 * 14 * 14 * 512);
    double* gpart = (double*)alloc(16 * 7 * 512);

    auto grid = [](int n, int b) { return (n + b - 1) / b; };

    // ---- fused pack (7 conv layers + dense) ----
    PackDesc pd;
    const float* pw[7] = {w2, w3, w4, w5, w6, w7, w8};
    u64* pwb[7] = {wb2, wb3, wb4, wb5, wb6, wb7, wb8};
    int pcinw[7] = {1, 2, 4, 4, 8, 8, 8};
    int pcout[7] = {128, 256, 256, 512, 512, 512, 512};
    int acc = 0;
    for (int L = 0; L < 7; ++L) {
        pd.w[L] = pw[L]; pd.wb[L] = pwb[L];
        pd.cinw[L] = pcinw[L]; pd.cout[L] = pcout[L];
        pd.start[L] = acc;
        acc += 9 * pcinw[L] * pcout[L];
    }
    pd.start[7] = acc;                       // 144000
    pack_all<<<grid(acc + 1000, 256), 256, 0, stream>>>(pd, dw, dwb);

    // ---- fused prep (7 BN layers; also writes tf1) ----
    PrepDesc qd;
    const float* qbn[7] = {bn1, bn2, bn3, bn4, bn5, bn6, bn7};
    double* qth[7] = {th1, th2, th3, th4, th5, th6, th7};
    int* qsf[7] = {sf1, sf2, sf3, sf4, sf5, sf6, sf7};
    int qcout[7] = {64, 128, 256, 256, 512, 512, 512};
    acc = 0;
    for (int L = 0; L < 7; ++L) {
        qd.bn[L] = qbn[L]; qd.thrd[L] = qth[L]; qd.sflag[L] = qsf[L];
        qd.cout[L] = qcout[L];
        qd.start[L] = acc;
        acc += qcout[L];
    }
    qd.start[7] = acc;                       // 2240
    prep_all<<<grid(acc, 256), 256, 0, stream>>>(qd, tf1);

    conv1_fused<<<16 * 112 * 28 / 4, 256, 0, stream>>>(inputs, w1, b1, tf1, th1, sf1, x2b);

    bconv<1, 128, 8, false><<<16 * 112 * 14, 128, 0, stream>>>(x2b, wb2, bn2, th2, sf2, c2b, nullptr, 112, 112);
    pool_bits<<<grid(16 * 56 * 56 * 2, 256), 256, 0, stream>>>(c2b, x3b, 56, 56, 2);
    bconv<2, 256, 8, false><<<16 * 56 * 7, 256, 0, stream>>>(x3b, wb3, bn3, th3, sf3, c3b, nullptr, 56, 56);
    bconv<4, 256, 8, false><<<16 * 56 * 7, 256, 0, stream>>>(c3b, wb4, bn4, th4, sf4, c4b, nullptr, 56, 56);
    pool_bits<<<grid(16 * 28 * 28 * 4, 256), 256, 0, stream>>>(c4b, x5b, 28, 28, 4);
    bconv<4, 512, 7, false><<<16 * 28 * 4, 512, 0, stream>>>(x5b, wb5, bn5, th5, sf5, c5b, nullptr, 28, 28);
    bconv<8, 512, 7, false><<<16 * 28 * 4, 512, 0, stream>>>(c5b, wb6, bn6, th6, sf6, c6b, nullptr, 28, 28);
    pool_bits<<<grid(16 * 14 * 14 * 8, 256), 256, 0, stream>>>(c6b, x7b, 14, 14, 8);
    bconv<8, 512, 7, false><<<16 * 14 * 2, 512, 0, stream>>>(x7b, wb7, bn7, th7, sf7, c7b, nullptr, 14, 14);
    bconv<8, 512, 7, true><<<16 * 14 * 2, 512, 0, stream>>>(c7b, wb8, bn8, nullptr, nullptr, nullptr, c8f, 14, 14);

    gap_part<<<16 * 7, 512, 0, stream>>>(c8f, gpart);
    gap_final<<<16, 512, 0, stream>>>(gpart, gb);
    dense_bin<<<grid(16000, 256), 256, 0, stream>>>(gb, dwb, out);
}